// Round 4
// baseline (356.100 us; speedup 1.0000x reference)
//
#include <hip/hip_runtime.h>
#include <stdint.h>

#define TW_N 2047
#define BATCH 8
#define T_LEN 65536
#define NCH 64
#define HID 512
#define NWIN (BATCH * TW_N) /* 16376 */

typedef unsigned short ushortT;

// ---------- bf16 pack helpers ----------
__device__ __forceinline__ ushortT f2b(float f) {
  union { float f; uint32_t i; } v; v.f = f;
  uint32_t r = v.i + 0x7fffu + ((v.i >> 16) & 1u);
  return (ushortT)(r >> 16);
}
__device__ __forceinline__ uint32_t pk2(float lo, float hi) {
  return (uint32_t)f2b(lo) | ((uint32_t)f2b(hi) << 16);
}

// ---------- async global->LDS, 16B per lane (dest linear in lane order) ----------
__device__ __forceinline__ void gload_lds16(const void* g, void* l) {
  __builtin_amdgcn_global_load_lds(
      (const __attribute__((address_space(1))) uint32_t*)g,
      (__attribute__((address_space(3))) uint32_t*)l, 16, 0, 0);
}

// ---------- compile-time DFT twiddles ----------
constexpr float CQ[17] = {
  1.0f, 0.9951847267f, 0.9807852804f, 0.9569403357f, 0.9238795325f,
  0.8819212643f, 0.8314696123f, 0.7730104534f, 0.7071067812f, 0.6343932842f,
  0.5555702330f, 0.4713967368f, 0.3826834324f, 0.2902846773f, 0.1950903220f,
  0.0980171403f, 0.0f };
constexpr float cos64(int m) {
  m &= 63;
  return (m <= 16) ? CQ[m] : (m < 32) ? -CQ[32 - m] : (m < 48) ? -CQ[m - 32] : CQ[64 - m];
}
constexpr float sin64(int m) { return cos64(m - 16); }
// odd k = 2i+1 (i<12): 32-term DFT over O.  even k = 2j (j=1..12): 16-term DFT
// over (j even ? ee : eo), twiddle w32^{jt} = w64^{2jt}.
struct Tw2 { float oc[12][32]; float os[12][32]; float ec[12][16]; float es[12][16]; };
constexpr Tw2 make2() {
  Tw2 t{};
  for (int i = 0; i < 12; ++i)
    for (int tt = 0; tt < 32; ++tt) {
      t.oc[i][tt] = cos64((2 * i + 1) * tt);
      t.os[i][tt] = sin64((2 * i + 1) * tt);
    }
  for (int j = 1; j <= 12; ++j)
    for (int tt = 0; tt < 16; ++tt) {
      t.ec[j - 1][tt] = cos64(2 * j * tt);
      t.es[j - 1][tt] = sin64(2 * j * tt);
    }
  return t;
}
constexpr Tw2 TW = make2();

// bf16-packed mix_w, written once per launch by prep_kernel
__device__ ushortT Bpack[HID * HID];   // 512 KB device-global

// ---------- K0: marker rows + mix_w fp32->bf16 pre-pack ----------
__global__ __launch_bounds__(256) void prep_kernel(
    const float* __restrict__ marker, const float* __restrict__ Bw,
    float* __restrict__ out)
{
  const int gid = blockIdx.x * 256 + threadIdx.x;
  if (blockIdx.x < 16) {
    out[(size_t)(gid >> 9) * (2048 * 512) + (gid & 511)] = marker[gid & 511];
  } else {
    const int i = (gid - 4096) * 8;
    const float4 f0 = *(const float4*)(Bw + i);
    const float4 f1 = *(const float4*)(Bw + i + 4);
    uint4 u;
    u.x = pk2(f0.x, f0.y); u.y = pk2(f0.z, f0.w);
    u.z = pk2(f1.x, f1.y); u.w = pk2(f1.z, f1.w);
    *(uint4*)(Bpack + i) = u;
  }
}

// ---------- K1: streaming features, role-swap double-buffer, 4 windows/wave ----------
// X = first half (dies into ee/eo, then receives prefetch), Y = second half
// (survives as next window's first half). O = odd part. 96 array VGPRs total.
#define WIN_BODY(X, Y, l, pf_ofs) do {                                        \
    float sum = 0.f, so2 = 0.f, se2 = 0.f;                                    \
    _Pragma("unroll")                                                         \
    for (int t = 0; t < 32; ++t) {                                            \
      O[t] = X[t] - Y[t];                                                     \
      X[t] = X[t] + Y[t];                                                     \
      so2 = fmaf(O[t], O[t], so2);                                            \
    }                                                                         \
    _Pragma("unroll")                                                         \
    for (int t = 0; t < 16; ++t) {            /* X[t]=ee, X[t+16]=eo */       \
      const float u = X[t] + X[t + 16], v = X[t] - X[t + 16];                 \
      X[t] = u; X[t + 16] = v;                                                \
      sum += u;                                                               \
      se2 = fmaf(u, u, fmaf(v, v, se2));                                      \
    }                                                                         \
    float b1 = 0.f, b2 = 0.f, b3 = 0.f, b4 = 0.f;                             \
    _Pragma("unroll")                                                         \
    for (int j = 1; j <= 12; ++j) {           /* even k = 2j */               \
      float re = 0.f, im = 0.f;                                               \
      _Pragma("unroll")                                                       \
      for (int t = 0; t < 16; ++t) {                                          \
        const float v = X[(j & 1) * 16 + t];  /* j odd -> eo */               \
        re = fmaf(v, TW.ec[j - 1][t], re);                                    \
        im = fmaf(v, TW.es[j - 1][t], im);                                    \
      }                                                                       \
      const float mag = __builtin_amdgcn_sqrtf(fmaf(re, re, im * im));        \
      const int k = 2 * j;                                                    \
      if (k < 4) b2 += mag; else if (k < 8) b3 += mag; else b4 += mag;        \
    }                                                                         \
    if ((pf_ofs) >= 0) {                      /* prefetch h_{pf_ofs} -> X */  \
      const float* pn = sg + (size_t)(pf_ofs) * (32 * NCH);                   \
      _Pragma("unroll")                                                       \
      for (int t = 0; t < 32; ++t) X[t] = pn[t * 64];                         \
    }                                                                         \
    _Pragma("unroll")                                                         \
    for (int i = 0; i < 12; ++i) {            /* odd k = 2i+1, over O */      \
      float re = 0.f, im = 0.f;                                               \
      _Pragma("unroll")                                                       \
      for (int t = 0; t < 32; ++t) {                                          \
        re = fmaf(O[t], TW.oc[i][t], re);                                     \
        im = fmaf(O[t], TW.os[i][t], im);                                     \
      }                                                                       \
      const float mag = __builtin_amdgcn_sqrtf(fmaf(re, re, im * im));        \
      const int k = 2 * i + 1;                                                \
      if (k == 1) b1 += mag;                                                  \
      else if (k < 4) b2 += mag;                                              \
      else if (k < 8) b3 += mag;                                              \
      else b4 += mag;                                                         \
    }                                                                         \
    const float mean = sum * (1.f / 64.f);                                    \
    const float var =                                                         \
        (se2 * 0.25f + so2 * 0.5f - sum * sum * (1.f / 64.f)) * (1.f / 63.f); \
    const float sd = __builtin_amdgcn_sqrtf(fmaxf(var, 0.f));                 \
    const float f1 = b1, f2 = b2 * 0.5f, f3 = b3 * 0.25f,                     \
                f4 = b4 * (1.f / 17.f);                                       \
    float emb[8];                                                             \
    _Pragma("unroll")                                                         \
    for (int p = 0; p < 8; ++p) {                                             \
      float e = cbp[p];                                                       \
      e = fmaf(f1, wr[8 + p], e);                                             \
      e = fmaf(f2, wr[16 + p], e);                                            \
      e = fmaf(f3, wr[24 + p], e);                                            \
      e = fmaf(f4, wr[32 + p], e);                                            \
      e = fmaf(mean, wr[40 + p], e);                                          \
      e = fmaf(sd, wr[48 + p], e);                                            \
      emb[p] = e;                                                             \
    }                                                                         \
    uint32_t pka[4];                                                          \
    _Pragma("unroll")                                                         \
    for (int q = 0; q < 4; ++q) pka[q] = pk2(emb[2 * q], emb[2 * q + 1]);     \
    *(uint4*)(flatB + (size_t)(wbase + (l)) * HID + c * 8) =                  \
        make_uint4(pka[0], pka[1], pka[2], pka[3]);                           \
  } while (0)

__global__ __launch_bounds__(256, 4) void feat_embed_kernel(
    const float* __restrict__ sig, const float* __restrict__ chw,
    const float* __restrict__ chb, ushortT* __restrict__ flatB)
{
  const int tid = threadIdx.x;
  const int c = tid & 63;
  const int gw = blockIdx.x * 4 + (tid >> 6);   // 0..4095
  const int b = gw >> 9;                        // batch
  const int r = gw & 511;
  int tw0 = r * 4;
  if (tw0 > TW_N - 4) tw0 = TW_N - 4;           // wave 511: windows 2043..2046
                                                // (2043 recomputed identically by wave 510 - benign)
  const int wbase = b * TW_N + tw0;
  const float* sg = sig + ((size_t)b * T_LEN + (size_t)tw0 * 32) * NCH + c;
  const float* wr = chw + c * 56;
  const float* cbp = chb + c * 8;

  float A[32], Bh[32], O[32];
#pragma unroll
  for (int t = 0; t < 32; ++t) A[t] = sg[t * 64];
#pragma unroll
  for (int t = 0; t < 32; ++t) Bh[t] = sg[(t + 32) * 64];

#pragma unroll 1
  for (int l = 0; l < 4; l += 2) {
    WIN_BODY(A, Bh, l, l + 2);                  // prefetch h_{l+2} -> A
    WIN_BODY(Bh, A, l + 1, (l == 0) ? 3 : -1);  // prefetch h3 -> Bh; skip h5
  }
}

// ---------- K2: z = flat @ mix_w^T + PE, depth-2 pipelined MFMA GEMM ----------
typedef __attribute__((ext_vector_type(8))) short short8;
typedef __attribute__((ext_vector_type(4))) float f32x4;

__global__ __launch_bounds__(256) void mix_gemm_kernel(
    const ushortT* __restrict__ A,    // flatB [16376][512] bf16 (ws)
    float* __restrict__ out)
{
  __shared__ ushortT As[3][128 * 32];  // 3-buffer ring, 8 KB each side
  __shared__ ushortT Bs[3][128 * 32];

  const int tid = threadIdx.x;
  const int lane = tid & 63;
  const int wv = tid >> 6;
  const int wm = wv >> 1, wn = wv & 1;
  const int fr = lane & 15;
  const int fq = lane >> 4;

  const int n0 = blockIdx.x * 128;   // 4 col-blocks
  const int m0 = blockIdx.y * 128;   // 128 row-blocks

  const int srow = tid >> 2;         // 64 rows per DMA pass
  const int sko = (tid & 3) * 8;     // k-offset in elements

  f32x4 acc[4][4];
#pragma unroll
  for (int i = 0; i < 4; ++i)
#pragma unroll
    for (int j = 0; j < 4; ++j) acc[i][j] = (f32x4){0.f, 0.f, 0.f, 0.f};

  int am0 = m0 + srow;       am0 = am0 < NWIN ? am0 : NWIN - 1;
  int am1 = m0 + 64 + srow;  am1 = am1 < NWIN ? am1 : NWIN - 1;
  const ushortT* ga0 = A + (size_t)am0 * HID + sko;
  const ushortT* ga1 = A + (size_t)am1 * HID + sko;
  const ushortT* gb0 = Bpack + (size_t)(n0 + srow) * HID + sko;
  const ushortT* gb1 = Bpack + (size_t)(n0 + 64 + srow) * HID + sko;

#define STAGE(buf, kt) do {                                                    \
    const int ko_ = (kt) * 32;                                                 \
    gload_lds16(ga0 + ko_, (char*)&As[buf][0] + tid * 16);                     \
    gload_lds16(ga1 + ko_, (char*)&As[buf][0] + 4096 + tid * 16);              \
    gload_lds16(gb0 + ko_, (char*)&Bs[buf][0] + tid * 16);                     \
    gload_lds16(gb1 + ko_, (char*)&Bs[buf][0] + 4096 + tid * 16);              \
  } while (0)

  STAGE(0, 0);
  STAGE(1, 1);

  int c0 = 0, c1 = 1, c2 = 2;   // ring: c0 = current, c2 = stage target
  for (int kt = 0; kt < 16; ++kt) {
    if (kt < 14) {
      STAGE(c2, kt + 2);
      // 8 DMAs (stages kt+1, kt+2) stay in flight; kt's 4 are complete
      asm volatile("s_waitcnt vmcnt(8)\n\ts_barrier" ::: "memory");
    } else if (kt == 14) {
      asm volatile("s_waitcnt vmcnt(4)\n\ts_barrier" ::: "memory");
    } else {
      asm volatile("s_waitcnt vmcnt(0)\n\ts_barrier" ::: "memory");
    }

    short8 af[4], bf[4];
#pragma unroll
    for (int mt = 0; mt < 4; ++mt)
      af[mt] = *(const short8*)&As[c0][(wm * 64 + mt * 16 + fr) * 32 + fq * 8];
#pragma unroll
    for (int nt = 0; nt < 4; ++nt)
      bf[nt] = *(const short8*)&Bs[c0][(wn * 64 + nt * 16 + fr) * 32 + fq * 8];
#pragma unroll
    for (int mt = 0; mt < 4; ++mt)
#pragma unroll
      for (int nt = 0; nt < 4; ++nt)
        acc[mt][nt] = __builtin_amdgcn_mfma_f32_16x16x32_bf16(af[mt], bf[nt], acc[mt][nt], 0, 0, 0);

    // all waves done reading buf c0 before anyone DMAs into it next iter
    asm volatile("s_barrier" ::: "memory");
    const int tmp = c0; c0 = c1; c1 = c2; c2 = tmp;
  }
#undef STAGE

  // epilogue (fp32 out): C/D layout col(n)=lane&15, row(m)=(lane>>4)*4+reg.
#pragma unroll
  for (int nt = 0; nt < 4; ++nt) {
    const int ng = n0 + wn * 64 + nt * 16 + fr;
    const float dv = __expf(-0.03597789208f * (float)(ng >> 1));
    const bool odd = (ng & 1);
#pragma unroll
    for (int mt = 0; mt < 4; ++mt) {
#pragma unroll
      for (int r = 0; r < 4; ++r) {
        const int mg = m0 + wm * 64 + mt * 16 + fq * 4 + r;
        if (mg < NWIN) {
          const int bb = mg / TW_N;
          const int tw = mg - bb * TW_N;
          const float ang = (float)tw * dv;
          const float pev = odd ? __cosf(ang) : __sinf(ang);
          out[((size_t)(bb * 2048 + 1 + tw)) * HID + ng] = acc[mt][nt][r] + pev;
        }
      }
    }
  }
}

extern "C" void kernel_launch(void* const* d_in, const int* in_sizes, int n_in,
                              void* d_out, int out_size, void* d_ws, size_t ws_size,
                              hipStream_t stream)
{
  const float* sig = (const float*)d_in[0];
  const float* chw = (const float*)d_in[1];
  const float* chb = (const float*)d_in[2];
  const float* mxw = (const float*)d_in[3];
  const float* mkr = (const float*)d_in[4];
  float* out = (float*)d_out;

  ushortT* flatB = (ushortT*)d_ws;

  hipLaunchKernelGGL(prep_kernel, dim3(144), dim3(256), 0, stream, mkr, mxw, out);
  hipLaunchKernelGGL(feat_embed_kernel, dim3(1024), dim3(256), 0, stream, sig, chw, chb, flatB);
  hipLaunchKernelGGL(mix_gemm_kernel, dim3(4, 128), dim3(256), 0, stream, flatB, out);
}

// Round 5
// 253.289 us; speedup vs baseline: 1.4059x; 1.4059x over previous
//
#include <hip/hip_runtime.h>
#include <stdint.h>

#define TW_N 2047
#define BATCH 8
#define T_LEN 65536
#define NCH 64
#define HID 512
#define NWIN (BATCH * TW_N) /* 16376 */

typedef unsigned short ushortT;

// ---------- bf16 pack helpers ----------
__device__ __forceinline__ ushortT f2b(float f) {
  union { float f; uint32_t i; } v; v.f = f;
  uint32_t r = v.i + 0x7fffu + ((v.i >> 16) & 1u);
  return (ushortT)(r >> 16);
}
__device__ __forceinline__ uint32_t pk2(float lo, float hi) {
  return (uint32_t)f2b(lo) | ((uint32_t)f2b(hi) << 16);
}

// ---------- async global->LDS, 16B per lane (dest linear in lane order) ----------
__device__ __forceinline__ void gload_lds16(const void* g, void* l) {
  __builtin_amdgcn_global_load_lds(
      (const __attribute__((address_space(1))) uint32_t*)g,
      (__attribute__((address_space(3))) uint32_t*)l, 16, 0, 0);
}

// ---------- compile-time DFT twiddles ----------
constexpr float CQ[17] = {
  1.0f, 0.9951847267f, 0.9807852804f, 0.9569403357f, 0.9238795325f,
  0.8819212643f, 0.8314696123f, 0.7730104534f, 0.7071067812f, 0.6343932842f,
  0.5555702330f, 0.4713967368f, 0.3826834324f, 0.2902846773f, 0.1950903220f,
  0.0980171403f, 0.0f };
constexpr float cos64(int m) {
  m &= 63;
  return (m <= 16) ? CQ[m] : (m < 32) ? -CQ[32 - m] : (m < 48) ? -CQ[m - 32] : CQ[64 - m];
}
constexpr float sin64(int m) { return cos64(m - 16); }
// odd k = 2i+1 (i<12): 32-term DFT over O.  even k = 2j (j=1..12): 16-term DFT
// over (j even ? ee : eo), twiddle w32^{jt} = w64^{2jt}.
struct Tw2 { float oc[12][32]; float os[12][32]; float ec[12][16]; float es[12][16]; };
constexpr Tw2 make2() {
  Tw2 t{};
  for (int i = 0; i < 12; ++i)
    for (int tt = 0; tt < 32; ++tt) {
      t.oc[i][tt] = cos64((2 * i + 1) * tt);
      t.os[i][tt] = sin64((2 * i + 1) * tt);
    }
  for (int j = 1; j <= 12; ++j)
    for (int tt = 0; tt < 16; ++tt) {
      t.ec[j - 1][tt] = cos64(2 * j * tt);
      t.es[j - 1][tt] = sin64(2 * j * tt);
    }
  return t;
}
constexpr Tw2 TW = make2();

// bf16-packed mix_w, written once per launch by prep_kernel
__device__ ushortT Bpack[HID * HID];   // 512 KB device-global

// ---------- K0: marker rows + mix_w fp32->bf16 pre-pack ----------
__global__ __launch_bounds__(256) void prep_kernel(
    const float* __restrict__ marker, const float* __restrict__ Bw,
    float* __restrict__ out)
{
  const int gid = blockIdx.x * 256 + threadIdx.x;
  if (blockIdx.x < 16) {
    out[(size_t)(gid >> 9) * (2048 * 512) + (gid & 511)] = marker[gid & 511];
  } else {
    const int i = (gid - 4096) * 8;
    const float4 f0 = *(const float4*)(Bw + i);
    const float4 f1 = *(const float4*)(Bw + i + 4);
    uint4 u;
    u.x = pk2(f0.x, f0.y); u.y = pk2(f0.z, f0.w);
    u.z = pk2(f1.x, f1.y); u.w = pk2(f1.z, f1.w);
    *(uint4*)(Bpack + i) = u;
  }
}

// ---------- K1: streaming features, role-swap double-buffer, 4 windows/wave ----------
// X = first half (dies into ee/eo, then receives prefetch in place), Y = second
// half (survives as next window's first half). O = odd part. 96 array VGPRs.
// sched_barrier(0) after the prefetch pins the loads BEFORE the odd-k DFT so
// ~1600 cycles of FMA always cover them (round-2 failure: loads sunk to use).
#define WIN_BODY(X, Y, l, pf_ofs) do {                                        \
    float sum = 0.f, so2 = 0.f, se2 = 0.f;                                    \
    _Pragma("unroll")                                                         \
    for (int t = 0; t < 32; ++t) {                                            \
      O[t] = X[t] - Y[t];                                                     \
      X[t] = X[t] + Y[t];                                                     \
      so2 = fmaf(O[t], O[t], so2);                                            \
    }                                                                         \
    _Pragma("unroll")                                                         \
    for (int t = 0; t < 16; ++t) {            /* X[t]=ee, X[t+16]=eo */       \
      const float u = X[t] + X[t + 16], v = X[t] - X[t + 16];                 \
      X[t] = u; X[t + 16] = v;                                                \
      sum += u;                                                               \
      se2 = fmaf(u, u, fmaf(v, v, se2));                                      \
    }                                                                         \
    float b1 = 0.f, b2 = 0.f, b3 = 0.f, b4 = 0.f;                             \
    _Pragma("unroll")                                                         \
    for (int j = 1; j <= 12; ++j) {           /* even k = 2j */               \
      float re = 0.f, im = 0.f;                                               \
      _Pragma("unroll")                                                       \
      for (int t = 0; t < 16; ++t) {                                          \
        const float v = X[(j & 1) * 16 + t];  /* j odd -> eo */               \
        re = fmaf(v, TW.ec[j - 1][t], re);                                    \
        im = fmaf(v, TW.es[j - 1][t], im);                                    \
      }                                                                       \
      const float mag = __builtin_amdgcn_sqrtf(fmaf(re, re, im * im));        \
      const int k = 2 * j;                                                    \
      if (k < 4) b2 += mag; else if (k < 8) b3 += mag; else b4 += mag;        \
    }                                                                         \
    if ((pf_ofs) >= 0) {                      /* prefetch h_{pf_ofs} -> X */  \
      const float* pn = sg + (size_t)(pf_ofs) * (32 * NCH);                   \
      _Pragma("unroll")                                                       \
      for (int t = 0; t < 32; ++t) X[t] = pn[t * 64];                         \
      __builtin_amdgcn_sched_barrier(0);      /* loads may not sink below */  \
    }                                                                         \
    _Pragma("unroll")                                                         \
    for (int i = 0; i < 12; ++i) {            /* odd k = 2i+1, over O */      \
      float re = 0.f, im = 0.f;                                               \
      _Pragma("unroll")                                                       \
      for (int t = 0; t < 32; ++t) {                                          \
        re = fmaf(O[t], TW.oc[i][t], re);                                     \
        im = fmaf(O[t], TW.os[i][t], im);                                     \
      }                                                                       \
      const float mag = __builtin_amdgcn_sqrtf(fmaf(re, re, im * im));        \
      const int k = 2 * i + 1;                                                \
      if (k == 1) b1 += mag;                                                  \
      else if (k < 4) b2 += mag;                                              \
      else if (k < 8) b3 += mag;                                              \
      else b4 += mag;                                                         \
    }                                                                         \
    const float mean = sum * (1.f / 64.f);                                    \
    const float var =                                                         \
        (se2 * 0.25f + so2 * 0.5f - sum * sum * (1.f / 64.f)) * (1.f / 63.f); \
    const float sd = __builtin_amdgcn_sqrtf(fmaxf(var, 0.f));                 \
    const float f1 = b1, f2 = b2 * 0.5f, f3 = b3 * 0.25f,                     \
                f4 = b4 * (1.f / 17.f);                                       \
    float emb[8];                                                             \
    _Pragma("unroll")                                                         \
    for (int p = 0; p < 8; ++p) {                                             \
      float e = cbp[p];                                                       \
      e = fmaf(f1, wr[8 + p], e);                                             \
      e = fmaf(f2, wr[16 + p], e);                                            \
      e = fmaf(f3, wr[24 + p], e);                                            \
      e = fmaf(f4, wr[32 + p], e);                                            \
      e = fmaf(mean, wr[40 + p], e);                                          \
      e = fmaf(sd, wr[48 + p], e);                                            \
      emb[p] = e;                                                             \
    }                                                                         \
    uint32_t pka[4];                                                          \
    _Pragma("unroll")                                                         \
    for (int q = 0; q < 4; ++q) pka[q] = pk2(emb[2 * q], emb[2 * q + 1]);     \
    *(uint4*)(flatB + (size_t)(wbase + (l)) * HID + c * 8) =                  \
        make_uint4(pka[0], pka[1], pka[2], pka[3]);                           \
  } while (0)

__global__ __launch_bounds__(256) void feat_embed_kernel(
    const float* __restrict__ sig, const float* __restrict__ chw,
    const float* __restrict__ chb, ushortT* __restrict__ flatB)
{
  const int tid = threadIdx.x;
  const int c = tid & 63;
  const int gw = blockIdx.x * 4 + (tid >> 6);   // 0..4095
  const int b = gw >> 9;                        // batch
  const int r = gw & 511;
  int tw0 = r * 4;
  if (tw0 > TW_N - 4) tw0 = TW_N - 4;           // wave 511: windows 2043..2046
                                                // (2043 recomputed identically by wave 510 - benign)
  const int wbase = b * TW_N + tw0;
  const float* sg = sig + ((size_t)b * T_LEN + (size_t)tw0 * 32) * NCH + c;
  const float* wr = chw + c * 56;
  const float* cbp = chb + c * 8;

  float A[32], Bh[32], O[32];
#pragma unroll
  for (int t = 0; t < 32; ++t) A[t] = sg[t * 64];
#pragma unroll
  for (int t = 0; t < 32; ++t) Bh[t] = sg[(t + 32) * 64];

#pragma unroll 1
  for (int l = 0; l < 4; l += 2) {
    WIN_BODY(A, Bh, l, l + 2);                  // prefetch h_{l+2} -> A
    WIN_BODY(Bh, A, l + 1, (l == 0) ? 3 : -1);  // prefetch h3 -> Bh; skip h5
  }
}

// ---------- K2: z = flat @ mix_w^T + PE, depth-2 pipelined MFMA GEMM ----------
typedef __attribute__((ext_vector_type(8))) short short8;
typedef __attribute__((ext_vector_type(4))) float f32x4;

__global__ __launch_bounds__(256) void mix_gemm_kernel(
    const ushortT* __restrict__ A,    // flatB [16376][512] bf16 (ws)
    float* __restrict__ out)
{
  __shared__ ushortT As[3][128 * 32];  // 3-buffer ring, 8 KB each side
  __shared__ ushortT Bs[3][128 * 32];

  const int tid = threadIdx.x;
  const int lane = tid & 63;
  const int wv = tid >> 6;
  const int wm = wv >> 1, wn = wv & 1;
  const int fr = lane & 15;
  const int fq = lane >> 4;

  const int n0 = blockIdx.x * 128;   // 4 col-blocks
  const int m0 = blockIdx.y * 128;   // 128 row-blocks

  const int srow = tid >> 2;         // 64 rows per DMA pass
  const int sko = (tid & 3) * 8;     // k-offset in elements

  f32x4 acc[4][4];
#pragma unroll
  for (int i = 0; i < 4; ++i)
#pragma unroll
    for (int j = 0; j < 4; ++j) acc[i][j] = (f32x4){0.f, 0.f, 0.f, 0.f};

  int am0 = m0 + srow;       am0 = am0 < NWIN ? am0 : NWIN - 1;
  int am1 = m0 + 64 + srow;  am1 = am1 < NWIN ? am1 : NWIN - 1;
  const ushortT* ga0 = A + (size_t)am0 * HID + sko;
  const ushortT* ga1 = A + (size_t)am1 * HID + sko;
  const ushortT* gb0 = Bpack + (size_t)(n0 + srow) * HID + sko;
  const ushortT* gb1 = Bpack + (size_t)(n0 + 64 + srow) * HID + sko;

#define STAGE(buf, kt) do {                                                    \
    const int ko_ = (kt) * 32;                                                 \
    gload_lds16(ga0 + ko_, (char*)&As[buf][0] + tid * 16);                     \
    gload_lds16(ga1 + ko_, (char*)&As[buf][0] + 4096 + tid * 16);              \
    gload_lds16(gb0 + ko_, (char*)&Bs[buf][0] + tid * 16);                     \
    gload_lds16(gb1 + ko_, (char*)&Bs[buf][0] + 4096 + tid * 16);              \
  } while (0)

  STAGE(0, 0);
  STAGE(1, 1);

  int c0 = 0, c1 = 1, c2 = 2;   // ring: c0 = current, c2 = stage target
  for (int kt = 0; kt < 16; ++kt) {
    if (kt < 14) {
      STAGE(c2, kt + 2);
      // 8 DMAs (stages kt+1, kt+2) stay in flight; kt's 4 are complete
      asm volatile("s_waitcnt vmcnt(8)\n\ts_barrier" ::: "memory");
    } else if (kt == 14) {
      asm volatile("s_waitcnt vmcnt(4)\n\ts_barrier" ::: "memory");
    } else {
      asm volatile("s_waitcnt vmcnt(0)\n\ts_barrier" ::: "memory");
    }

    short8 af[4], bf[4];
#pragma unroll
    for (int mt = 0; mt < 4; ++mt)
      af[mt] = *(const short8*)&As[c0][(wm * 64 + mt * 16 + fr) * 32 + fq * 8];
#pragma unroll
    for (int nt = 0; nt < 4; ++nt)
      bf[nt] = *(const short8*)&Bs[c0][(wn * 64 + nt * 16 + fr) * 32 + fq * 8];
#pragma unroll
    for (int mt = 0; mt < 4; ++mt)
#pragma unroll
      for (int nt = 0; nt < 4; ++nt)
        acc[mt][nt] = __builtin_amdgcn_mfma_f32_16x16x32_bf16(af[mt], bf[nt], acc[mt][nt], 0, 0, 0);

    // all waves done reading buf c0 before anyone DMAs into it next iter
    asm volatile("s_barrier" ::: "memory");
    const int tmp = c0; c0 = c1; c1 = c2; c2 = tmp;
  }
#undef STAGE

  // epilogue (fp32 out): C/D layout col(n)=lane&15, row(m)=(lane>>4)*4+reg.
#pragma unroll
  for (int nt = 0; nt < 4; ++nt) {
    const int ng = n0 + wn * 64 + nt * 16 + fr;
    const float dv = __expf(-0.03597789208f * (float)(ng >> 1));
    const bool odd = (ng & 1);
#pragma unroll
    for (int mt = 0; mt < 4; ++mt) {
#pragma unroll
      for (int r = 0; r < 4; ++r) {
        const int mg = m0 + wm * 64 + mt * 16 + fq * 4 + r;
        if (mg < NWIN) {
          const int bb = mg / TW_N;
          const int tw = mg - bb * TW_N;
          const float ang = (float)tw * dv;
          const float pev = odd ? __cosf(ang) : __sinf(ang);
          out[((size_t)(bb * 2048 + 1 + tw)) * HID + ng] = acc[mt][nt][r] + pev;
        }
      }
    }
  }
}

extern "C" void kernel_launch(void* const* d_in, const int* in_sizes, int n_in,
                              void* d_out, int out_size, void* d_ws, size_t ws_size,
                              hipStream_t stream)
{
  const float* sig = (const float*)d_in[0];
  const float* chw = (const float*)d_in[1];
  const float* chb = (const float*)d_in[2];
  const float* mxw = (const float*)d_in[3];
  const float* mkr = (const float*)d_in[4];
  float* out = (float*)d_out;

  ushortT* flatB = (ushortT*)d_ws;

  hipLaunchKernelGGL(prep_kernel, dim3(144), dim3(256), 0, stream, mkr, mxw, out);
  hipLaunchKernelGGL(feat_embed_kernel, dim3(1024), dim3(256), 0, stream, sig, chw, chb, flatB);
  hipLaunchKernelGGL(mix_gemm_kernel, dim3(4, 128), dim3(256), 0, stream, flatB, out);
}

// Round 6
// 240.566 us; speedup vs baseline: 1.4803x; 1.0529x over previous
//
#include <hip/hip_runtime.h>
#include <stdint.h>

#define TW_N 2047
#define BATCH 8
#define T_LEN 65536
#define NCH 64
#define HID 512
#define NWIN (BATCH * TW_N) /* 16376 */

typedef unsigned short ushortT;

// ---------- bf16 pack helpers ----------
__device__ __forceinline__ ushortT f2b(float f) {
  union { float f; uint32_t i; } v; v.f = f;
  uint32_t r = v.i + 0x7fffu + ((v.i >> 16) & 1u);
  return (ushortT)(r >> 16);
}
__device__ __forceinline__ uint32_t pk2(float lo, float hi) {
  return (uint32_t)f2b(lo) | ((uint32_t)f2b(hi) << 16);
}

// ---------- async global->LDS, 16B per lane (dest linear in lane order) ----------
__device__ __forceinline__ void gload_lds16(const void* g, void* l) {
  __builtin_amdgcn_global_load_lds(
      (const __attribute__((address_space(1))) uint32_t*)g,
      (__attribute__((address_space(3))) uint32_t*)l, 16, 0, 0);
}

// ---------- compile-time DFT twiddles ----------
constexpr float CQ[17] = {
  1.0f, 0.9951847267f, 0.9807852804f, 0.9569403357f, 0.9238795325f,
  0.8819212643f, 0.8314696123f, 0.7730104534f, 0.7071067812f, 0.6343932842f,
  0.5555702330f, 0.4713967368f, 0.3826834324f, 0.2902846773f, 0.1950903220f,
  0.0980171403f, 0.0f };
constexpr float cos64(int m) {
  m &= 63;
  return (m <= 16) ? CQ[m] : (m < 32) ? -CQ[32 - m] : (m < 48) ? -CQ[m - 32] : CQ[64 - m];
}
constexpr float sin64(int m) { return cos64(m - 16); }
// odd k = 2i+1 (i<12): 32-term DFT over o = X-Y (inline, no O array).
// even k = 2j (j=1..12): 16-term DFT over (j even ? u : v), twiddle w64^{2jt}.
struct Tw2 { float oc[12][32]; float os[12][32]; float ec[12][16]; float es[12][16]; };
constexpr Tw2 make2() {
  Tw2 t{};
  for (int i = 0; i < 12; ++i)
    for (int tt = 0; tt < 32; ++tt) {
      t.oc[i][tt] = cos64((2 * i + 1) * tt);
      t.os[i][tt] = sin64((2 * i + 1) * tt);
    }
  for (int j = 1; j <= 12; ++j)
    for (int tt = 0; tt < 16; ++tt) {
      t.ec[j - 1][tt] = cos64(2 * j * tt);
      t.es[j - 1][tt] = sin64(2 * j * tt);
    }
  return t;
}
constexpr Tw2 TW = make2();

// bf16-packed mix_w, written once per launch by prep_kernel
__device__ ushortT Bpack[HID * HID];   // 512 KB device-global

// ---------- K0: marker rows + mix_w fp32->bf16 pre-pack ----------
__global__ __launch_bounds__(256) void prep_kernel(
    const float* __restrict__ marker, const float* __restrict__ Bw,
    float* __restrict__ out)
{
  const int gid = blockIdx.x * 256 + threadIdx.x;
  if (blockIdx.x < 16) {
    out[(size_t)(gid >> 9) * (2048 * 512) + (gid & 511)] = marker[gid & 511];
  } else {
    const int i = (gid - 4096) * 8;
    const float4 f0 = *(const float4*)(Bw + i);
    const float4 f1 = *(const float4*)(Bw + i + 4);
    uint4 u;
    u.x = pk2(f0.x, f0.y); u.y = pk2(f0.z, f0.w);
    u.z = pk2(f1.x, f1.y); u.w = pk2(f1.z, f1.w);
    *(uint4*)(Bpack + i) = u;
  }
}

// ---------- K1: streaming features, NO O-array (t-outer DFTs), 4 windows/wave ----
// Roles per window: X = h_l (consumed; then prefetch target), Y = h_{l+1}
// (read-only, survives as next window's X). Peak regs ~110 -> 4 waves/SIMD.
// Order: odd accums (o = X-Y inline) -> odd mags -> butterfly X+=Y ->
// 2nd butterfly -> even accums (X dies) -> prefetch into X -> even mags/emb.
#define WIN_BODY(X, Y, l, pf_ofs) do {                                        \
    float ro[12], io[12];                                                     \
    _Pragma("unroll")                                                         \
    for (int i = 0; i < 12; ++i) { ro[i] = 0.f; io[i] = 0.f; }                \
    float so2 = 0.f;                                                          \
    _Pragma("unroll")                                                         \
    for (int t = 0; t < 32; ++t) {                                            \
      const float o = X[t] - Y[t];                                            \
      so2 = fmaf(o, o, so2);                                                  \
      _Pragma("unroll")                                                       \
      for (int i = 0; i < 12; ++i) {                                          \
        ro[i] = fmaf(o, TW.oc[i][t], ro[i]);                                  \
        io[i] = fmaf(o, TW.os[i][t], io[i]);                                  \
      }                                                                       \
    }                                                                         \
    float b1 = 0.f, b2 = 0.f, b3 = 0.f, b4 = 0.f;                             \
    _Pragma("unroll")                                                         \
    for (int i = 0; i < 12; ++i) {            /* odd mags: ro/io die here */  \
      const float mag =                                                       \
          __builtin_amdgcn_sqrtf(fmaf(ro[i], ro[i], io[i] * io[i]));          \
      const int k = 2 * i + 1;                                                \
      if (k == 1) b1 += mag;                                                  \
      else if (k < 4) b2 += mag;                                              \
      else if (k < 8) b3 += mag;                                              \
      else b4 += mag;                                                         \
    }                                                                         \
    float sum = 0.f, se2 = 0.f;                                               \
    _Pragma("unroll")                                                         \
    for (int t = 0; t < 32; ++t) X[t] += Y[t];     /* X = e; Y intact */      \
    _Pragma("unroll")                                                         \
    for (int t = 0; t < 16; ++t) {            /* X[t]=u, X[t+16]=v */         \
      const float u = X[t] + X[t + 16], v = X[t] - X[t + 16];                 \
      X[t] = u; X[t + 16] = v;                                                \
      sum += u;                                                               \
      se2 = fmaf(u, u, fmaf(v, v, se2));                                      \
    }                                                                         \
    float re_[12], ie_[12];                                                   \
    _Pragma("unroll")                                                         \
    for (int j = 0; j < 12; ++j) { re_[j] = 0.f; ie_[j] = 0.f; }              \
    _Pragma("unroll")                                                         \
    for (int t = 0; t < 16; ++t) {                                            \
      _Pragma("unroll")                                                       \
      for (int j = 1; j <= 12; ++j) {         /* j odd -> v, j even -> u */   \
        const float vv = X[(j & 1) * 16 + t];                                 \
        re_[j - 1] = fmaf(vv, TW.ec[j - 1][t], re_[j - 1]);                   \
        ie_[j - 1] = fmaf(vv, TW.es[j - 1][t], ie_[j - 1]);                   \
      }                                                                       \
    }                                                                         \
    if ((pf_ofs) >= 0) {                      /* X dead: prefetch h_{pf} */   \
      const float* pn = sg + (size_t)(pf_ofs) * (32 * NCH);                   \
      _Pragma("unroll")                                                       \
      for (int t = 0; t < 32; ++t) X[t] = pn[t * 64];                         \
      __builtin_amdgcn_sched_barrier(0);      /* loads may not sink below */  \
    }                                                                         \
    _Pragma("unroll")                                                         \
    for (int j = 1; j <= 12; ++j) {           /* even mags (cover loads) */   \
      const float mag = __builtin_amdgcn_sqrtf(                               \
          fmaf(re_[j - 1], re_[j - 1], ie_[j - 1] * ie_[j - 1]));             \
      const int k = 2 * j;                                                    \
      if (k < 4) b2 += mag; else if (k < 8) b3 += mag; else b4 += mag;        \
    }                                                                         \
    const float mean = sum * (1.f / 64.f);                                    \
    const float var =                                                         \
        (se2 * 0.25f + so2 * 0.5f - sum * sum * (1.f / 64.f)) * (1.f / 63.f); \
    const float sd = __builtin_amdgcn_sqrtf(fmaxf(var, 0.f));                 \
    const float f1 = b1, f2 = b2 * 0.5f, f3 = b3 * 0.25f,                     \
                f4 = b4 * (1.f / 17.f);                                       \
    float emb[8];                                                             \
    _Pragma("unroll")                                                         \
    for (int p = 0; p < 8; ++p) {                                             \
      float e = cbp[p];                                                       \
      e = fmaf(f1, wr[8 + p], e);                                             \
      e = fmaf(f2, wr[16 + p], e);                                            \
      e = fmaf(f3, wr[24 + p], e);                                            \
      e = fmaf(f4, wr[32 + p], e);                                            \
      e = fmaf(mean, wr[40 + p], e);                                          \
      e = fmaf(sd, wr[48 + p], e);                                            \
      emb[p] = e;                                                             \
    }                                                                         \
    uint32_t pka[4];                                                          \
    _Pragma("unroll")                                                         \
    for (int q = 0; q < 4; ++q) pka[q] = pk2(emb[2 * q], emb[2 * q + 1]);     \
    *(uint4*)(flatB + (size_t)(wbase + (l)) * HID + c * 8) =                  \
        make_uint4(pka[0], pka[1], pka[2], pka[3]);                           \
  } while (0)

__global__ __launch_bounds__(256) void feat_embed_kernel(
    const float* __restrict__ sig, const float* __restrict__ chw,
    const float* __restrict__ chb, ushortT* __restrict__ flatB)
{
  const int tid = threadIdx.x;
  const int c = tid & 63;
  const int gw = blockIdx.x * 4 + (tid >> 6);   // 0..4095
  const int b = gw >> 9;                        // batch
  const int r = gw & 511;
  int tw0 = r * 4;
  if (tw0 > TW_N - 4) tw0 = TW_N - 4;           // wave 511: windows 2043..2046
                                                // (2043 recomputed identically by wave 510 - benign)
  const int wbase = b * TW_N + tw0;
  const float* sg = sig + ((size_t)b * T_LEN + (size_t)tw0 * 32) * NCH + c;
  const float* wr = chw + c * 56;
  const float* cbp = chb + c * 8;

  float A[32], Bh[32];
#pragma unroll
  for (int t = 0; t < 32; ++t) A[t] = sg[t * 64];
#pragma unroll
  for (int t = 0; t < 32; ++t) Bh[t] = sg[(t + 32) * 64];

  // windows l=0..3: roles alternate; prefetch h_{l+2} into the dying buffer.
  // Max prefetch row: (2043+4)*32+31 = 65535 < T_LEN. Last window: no prefetch.
#pragma unroll 1
  for (int l = 0; l < 4; l += 2) {
    WIN_BODY(A, Bh, l, l + 2);                      // h_{l+2} -> A
    WIN_BODY(Bh, A, l + 1, (l == 2) ? -1 : l + 3);  // h_{l+3} -> Bh (skip last)
  }
}

// ---------- K2: z = flat @ mix_w^T + PE, depth-2 pipelined MFMA GEMM ----------
typedef __attribute__((ext_vector_type(8))) short short8;
typedef __attribute__((ext_vector_type(4))) float f32x4;

__global__ __launch_bounds__(256) void mix_gemm_kernel(
    const ushortT* __restrict__ A,    // flatB [16376][512] bf16 (ws)
    float* __restrict__ out)
{
  __shared__ ushortT As[3][128 * 32];  // 3-buffer ring, 8 KB each side
  __shared__ ushortT Bs[3][128 * 32];

  const int tid = threadIdx.x;
  const int lane = tid & 63;
  const int wv = tid >> 6;
  const int wm = wv >> 1, wn = wv & 1;
  const int fr = lane & 15;
  const int fq = lane >> 4;

  const int n0 = blockIdx.x * 128;   // 4 col-blocks
  const int m0 = blockIdx.y * 128;   // 128 row-blocks

  const int srow = tid >> 2;         // 64 rows per DMA pass
  const int sko = (tid & 3) * 8;     // k-offset in elements

  f32x4 acc[4][4];
#pragma unroll
  for (int i = 0; i < 4; ++i)
#pragma unroll
    for (int j = 0; j < 4; ++j) acc[i][j] = (f32x4){0.f, 0.f, 0.f, 0.f};

  int am0 = m0 + srow;       am0 = am0 < NWIN ? am0 : NWIN - 1;
  int am1 = m0 + 64 + srow;  am1 = am1 < NWIN ? am1 : NWIN - 1;
  const ushortT* ga0 = A + (size_t)am0 * HID + sko;
  const ushortT* ga1 = A + (size_t)am1 * HID + sko;
  const ushortT* gb0 = Bpack + (size_t)(n0 + srow) * HID + sko;
  const ushortT* gb1 = Bpack + (size_t)(n0 + 64 + srow) * HID + sko;

#define STAGE(buf, kt) do {                                                    \
    const int ko_ = (kt) * 32;                                                 \
    gload_lds16(ga0 + ko_, (char*)&As[buf][0] + tid * 16);                     \
    gload_lds16(ga1 + ko_, (char*)&As[buf][0] + 4096 + tid * 16);              \
    gload_lds16(gb0 + ko_, (char*)&Bs[buf][0] + tid * 16);                     \
    gload_lds16(gb1 + ko_, (char*)&Bs[buf][0] + 4096 + tid * 16);              \
  } while (0)

  STAGE(0, 0);
  STAGE(1, 1);

  int c0 = 0, c1 = 1, c2 = 2;   // ring: c0 = current, c2 = stage target
  for (int kt = 0; kt < 16; ++kt) {
    if (kt < 14) {
      STAGE(c2, kt + 2);
      // 8 DMAs (stages kt+1, kt+2) stay in flight; kt's 4 are complete
      asm volatile("s_waitcnt vmcnt(8)\n\ts_barrier" ::: "memory");
    } else if (kt == 14) {
      asm volatile("s_waitcnt vmcnt(4)\n\ts_barrier" ::: "memory");
    } else {
      asm volatile("s_waitcnt vmcnt(0)\n\ts_barrier" ::: "memory");
    }

    short8 af[4], bf[4];
#pragma unroll
    for (int mt = 0; mt < 4; ++mt)
      af[mt] = *(const short8*)&As[c0][(wm * 64 + mt * 16 + fr) * 32 + fq * 8];
#pragma unroll
    for (int nt = 0; nt < 4; ++nt)
      bf[nt] = *(const short8*)&Bs[c0][(wn * 64 + nt * 16 + fr) * 32 + fq * 8];
#pragma unroll
    for (int mt = 0; mt < 4; ++mt)
#pragma unroll
      for (int nt = 0; nt < 4; ++nt)
        acc[mt][nt] = __builtin_amdgcn_mfma_f32_16x16x32_bf16(af[mt], bf[nt], acc[mt][nt], 0, 0, 0);

    // all waves done reading buf c0 before anyone DMAs into it next iter
    asm volatile("s_barrier" ::: "memory");
    const int tmp = c0; c0 = c1; c1 = c2; c2 = tmp;
  }
#undef STAGE

  // epilogue (fp32 out): C/D layout col(n)=lane&15, row(m)=(lane>>4)*4+reg.
#pragma unroll
  for (int nt = 0; nt < 4; ++nt) {
    const int ng = n0 + wn * 64 + nt * 16 + fr;
    const float dv = __expf(-0.03597789208f * (float)(ng >> 1));
    const bool odd = (ng & 1);
#pragma unroll
    for (int mt = 0; mt < 4; ++mt) {
#pragma unroll
      for (int r = 0; r < 4; ++r) {
        const int mg = m0 + wm * 64 + mt * 16 + fq * 4 + r;
        if (mg < NWIN) {
          const int bb = mg / TW_N;
          const int tw = mg - bb * TW_N;
          const float ang = (float)tw * dv;
          const float pev = odd ? __cosf(ang) : __sinf(ang);
          out[((size_t)(bb * 2048 + 1 + tw)) * HID + ng] = acc[mt][nt][r] + pev;
        }
      }
    }
  }
}

extern "C" void kernel_launch(void* const* d_in, const int* in_sizes, int n_in,
                              void* d_out, int out_size, void* d_ws, size_t ws_size,
                              hipStream_t stream)
{
  const float* sig = (const float*)d_in[0];
  const float* chw = (const float*)d_in[1];
  const float* chb = (const float*)d_in[2];
  const float* mxw = (const float*)d_in[3];
  const float* mkr = (const float*)d_in[4];
  float* out = (float*)d_out;

  ushortT* flatB = (ushortT*)d_ws;

  hipLaunchKernelGGL(prep_kernel, dim3(144), dim3(256), 0, stream, mkr, mxw, out);
  hipLaunchKernelGGL(feat_embed_kernel, dim3(1024), dim3(256), 0, stream, sig, chw, chb, flatB);
  hipLaunchKernelGGL(mix_gemm_kernel, dim3(4, 128), dim3(256), 0, stream, flatB, out);
}

// Round 7
// 240.303 us; speedup vs baseline: 1.4819x; 1.0011x over previous
//
#include <hip/hip_runtime.h>
#include <stdint.h>

#define TW_N 2047
#define BATCH 8
#define T_LEN 65536
#define NCH 64
#define HID 512
#define NWIN (BATCH * TW_N) /* 16376 */

typedef unsigned short ushortT;

// ---------- bf16 pack helpers ----------
__device__ __forceinline__ ushortT f2b(float f) {
  union { float f; uint32_t i; } v; v.f = f;
  uint32_t r = v.i + 0x7fffu + ((v.i >> 16) & 1u);
  return (ushortT)(r >> 16);
}
__device__ __forceinline__ uint32_t pk2(float lo, float hi) {
  return (uint32_t)f2b(lo) | ((uint32_t)f2b(hi) << 16);
}

// ---------- async global->LDS, 16B per lane (dest linear in lane order) ----------
__device__ __forceinline__ void gload_lds16(const void* g, void* l) {
  __builtin_amdgcn_global_load_lds(
      (const __attribute__((address_space(1))) uint32_t*)g,
      (__attribute__((address_space(3))) uint32_t*)l, 16, 0, 0);
}

// ---------- compile-time DFT twiddles ----------
constexpr float CQ[17] = {
  1.0f, 0.9951847267f, 0.9807852804f, 0.9569403357f, 0.9238795325f,
  0.8819212643f, 0.8314696123f, 0.7730104534f, 0.7071067812f, 0.6343932842f,
  0.5555702330f, 0.4713967368f, 0.3826834324f, 0.2902846773f, 0.1950903220f,
  0.0980171403f, 0.0f };
constexpr float cos64(int m) {
  m &= 63;
  return (m <= 16) ? CQ[m] : (m < 32) ? -CQ[32 - m] : (m < 48) ? -CQ[m - 32] : CQ[64 - m];
}
constexpr float sin64(int m) { return cos64(m - 16); }
// odd k = 2i+1 (i<12): 32-term DFT over o.  even k = 2j (j=1..12): 16-term DFT
// over (j even ? u : v), twiddle w64^{2jt}.
struct Tw2 { float oc[12][32]; float os[12][32]; float ec[12][16]; float es[12][16]; };
constexpr Tw2 make2() {
  Tw2 t{};
  for (int i = 0; i < 12; ++i)
    for (int tt = 0; tt < 32; ++tt) {
      t.oc[i][tt] = cos64((2 * i + 1) * tt);
      t.os[i][tt] = sin64((2 * i + 1) * tt);
    }
  for (int j = 1; j <= 12; ++j)
    for (int tt = 0; tt < 16; ++tt) {
      t.ec[j - 1][tt] = cos64(2 * j * tt);
      t.es[j - 1][tt] = sin64(2 * j * tt);
    }
  return t;
}
constexpr Tw2 TW = make2();

// bf16-packed mix_w, written once per launch by prep_kernel
__device__ ushortT Bpack[HID * HID];   // 512 KB device-global

// ---------- K0: marker rows + mix_w fp32->bf16 pre-pack ----------
__global__ __launch_bounds__(256) void prep_kernel(
    const float* __restrict__ marker, const float* __restrict__ Bw,
    float* __restrict__ out)
{
  const int gid = blockIdx.x * 256 + threadIdx.x;
  if (blockIdx.x < 16) {
    out[(size_t)(gid >> 9) * (2048 * 512) + (gid & 511)] = marker[gid & 511];
  } else {
    const int i = (gid - 4096) * 8;
    const float4 f0 = *(const float4*)(Bw + i);
    const float4 f1 = *(const float4*)(Bw + i + 4);
    uint4 u;
    u.x = pk2(f0.x, f0.y); u.y = pk2(f0.z, f0.w);
    u.z = pk2(f1.x, f1.y); u.w = pk2(f1.z, f1.w);
    *(uint4*)(Bpack + i) = u;
  }
}

// ---------- K1: one window per wave, straight-line, lane = channel ----------
// Peak live set: X(32, e then u/v) + Y(32, o) + 24 accums + temps ~= 105 VGPR.
// amdgpu_waves_per_eu(4) pins VGPR <= 128 -> 4 waves/SIMD (16 waves/CU).
// grid 4094 x 4 waves = 16376 windows exactly; no tail, no clamps.
__global__ __launch_bounds__(256) __attribute__((amdgpu_waves_per_eu(4)))
void feat_embed_kernel(
    const float* __restrict__ sig, const float* __restrict__ chw,
    const float* __restrict__ chb, ushortT* __restrict__ flatB)
{
  const int tid = threadIdx.x;
  const int c = tid & 63;
  const int w = blockIdx.x * 4 + (tid >> 6);    // 0..16375
  const int b = w / TW_N;
  const int tw = w - b * TW_N;
  const float* sg = sig + ((size_t)b * T_LEN + (size_t)tw * 32) * NCH + c;
  const float* wr = chw + c * 56;
  const float* cbp = chb + c * 8;

  float X[32], Y[32];
#pragma unroll
  for (int t = 0; t < 32; ++t) X[t] = sg[t * 64];
#pragma unroll
  for (int t = 0; t < 32; ++t) Y[t] = sg[(t + 32) * 64];

  // butterfly in place: X <- e = a+d, Y <- o = a-d (raw samples die here)
  float sum = 0.f, so2 = 0.f, se2 = 0.f;
#pragma unroll
  for (int t = 0; t < 32; ++t) {
    const float e = X[t] + Y[t];
    const float o = X[t] - Y[t];
    X[t] = e; Y[t] = o;
    so2 = fmaf(o, o, so2);
  }
  // second butterfly on e: X[t]=u, X[t+16]=v
#pragma unroll
  for (int t = 0; t < 16; ++t) {
    const float u = X[t] + X[t + 16], v = X[t] - X[t + 16];
    X[t] = u; X[t + 16] = v;
    sum += u;
    se2 = fmaf(u, u, fmaf(v, v, se2));
  }

  // odd k = 2i+1: 32-term DFT over Y = o (t-outer, 24 independent FMA chains)
  float ro[12], io[12];
#pragma unroll
  for (int i = 0; i < 12; ++i) { ro[i] = 0.f; io[i] = 0.f; }
#pragma unroll
  for (int t = 0; t < 32; ++t) {
    const float o = Y[t];
#pragma unroll
    for (int i = 0; i < 12; ++i) {
      ro[i] = fmaf(o, TW.oc[i][t], ro[i]);
      io[i] = fmaf(o, TW.os[i][t], io[i]);
    }
  }
  float b1 = 0.f, b2 = 0.f, b3 = 0.f, b4 = 0.f;
#pragma unroll
  for (int i = 0; i < 12; ++i) {               // odd mags; ro/io + Y die
    const float mag = __builtin_amdgcn_sqrtf(fmaf(ro[i], ro[i], io[i] * io[i]));
    const int k = 2 * i + 1;
    if (k == 1) b1 += mag;
    else if (k < 4) b2 += mag;
    else if (k < 8) b3 += mag;
    else b4 += mag;
  }

  // even k = 2j: 16-term DFT over (j odd ? v : u)
  float re_[12], ie_[12];
#pragma unroll
  for (int j = 0; j < 12; ++j) { re_[j] = 0.f; ie_[j] = 0.f; }
#pragma unroll
  for (int t = 0; t < 16; ++t) {
#pragma unroll
    for (int j = 1; j <= 12; ++j) {
      const float vv = X[(j & 1) * 16 + t];
      re_[j - 1] = fmaf(vv, TW.ec[j - 1][t], re_[j - 1]);
      ie_[j - 1] = fmaf(vv, TW.es[j - 1][t], ie_[j - 1]);
    }
  }
#pragma unroll
  for (int j = 1; j <= 12; ++j) {              // even mags
    const float mag = __builtin_amdgcn_sqrtf(
        fmaf(re_[j - 1], re_[j - 1], ie_[j - 1] * ie_[j - 1]));
    const int k = 2 * j;
    if (k < 4) b2 += mag; else if (k < 8) b3 += mag; else b4 += mag;
  }

  const float mean = sum * (1.f / 64.f);
  const float var =
      (se2 * 0.25f + so2 * 0.5f - sum * sum * (1.f / 64.f)) * (1.f / 63.f);
  const float sd = __builtin_amdgcn_sqrtf(fmaxf(var, 0.f));

  const float f1 = b1, f2 = b2 * 0.5f, f3 = b3 * 0.25f, f4 = b4 * (1.f / 17.f);
  float emb[8];
#pragma unroll
  for (int p = 0; p < 8; ++p) {
    float e = cbp[p];
    e = fmaf(f1, wr[8 + p], e);
    e = fmaf(f2, wr[16 + p], e);
    e = fmaf(f3, wr[24 + p], e);
    e = fmaf(f4, wr[32 + p], e);
    e = fmaf(mean, wr[40 + p], e);
    e = fmaf(sd, wr[48 + p], e);
    emb[p] = e;
  }

  uint32_t pka[4];
#pragma unroll
  for (int q = 0; q < 4; ++q) pka[q] = pk2(emb[2 * q], emb[2 * q + 1]);
  *(uint4*)(flatB + (size_t)w * HID + c * 8) = make_uint4(pka[0], pka[1], pka[2], pka[3]);
}

// ---------- K2: z = flat @ mix_w^T + PE, depth-2 pipelined MFMA GEMM ----------
typedef __attribute__((ext_vector_type(8))) short short8;
typedef __attribute__((ext_vector_type(4))) float f32x4;

__global__ __launch_bounds__(256) void mix_gemm_kernel(
    const ushortT* __restrict__ A,    // flatB [16376][512] bf16 (ws)
    float* __restrict__ out)
{
  __shared__ ushortT As[3][128 * 32];  // 3-buffer ring, 8 KB each side
  __shared__ ushortT Bs[3][128 * 32];

  const int tid = threadIdx.x;
  const int lane = tid & 63;
  const int wv = tid >> 6;
  const int wm = wv >> 1, wn = wv & 1;
  const int fr = lane & 15;
  const int fq = lane >> 4;

  const int n0 = blockIdx.x * 128;   // 4 col-blocks
  const int m0 = blockIdx.y * 128;   // 128 row-blocks

  const int srow = tid >> 2;         // 64 rows per DMA pass
  const int sko = (tid & 3) * 8;     // k-offset in elements

  f32x4 acc[4][4];
#pragma unroll
  for (int i = 0; i < 4; ++i)
#pragma unroll
    for (int j = 0; j < 4; ++j) acc[i][j] = (f32x4){0.f, 0.f, 0.f, 0.f};

  int am0 = m0 + srow;       am0 = am0 < NWIN ? am0 : NWIN - 1;
  int am1 = m0 + 64 + srow;  am1 = am1 < NWIN ? am1 : NWIN - 1;
  const ushortT* ga0 = A + (size_t)am0 * HID + sko;
  const ushortT* ga1 = A + (size_t)am1 * HID + sko;
  const ushortT* gb0 = Bpack + (size_t)(n0 + srow) * HID + sko;
  const ushortT* gb1 = Bpack + (size_t)(n0 + 64 + srow) * HID + sko;

#define STAGE(buf, kt) do {                                                    \
    const int ko_ = (kt) * 32;                                                 \
    gload_lds16(ga0 + ko_, (char*)&As[buf][0] + tid * 16);                     \
    gload_lds16(ga1 + ko_, (char*)&As[buf][0] + 4096 + tid * 16);              \
    gload_lds16(gb0 + ko_, (char*)&Bs[buf][0] + tid * 16);                     \
    gload_lds16(gb1 + ko_, (char*)&Bs[buf][0] + 4096 + tid * 16);              \
  } while (0)

  STAGE(0, 0);
  STAGE(1, 1);

  int c0 = 0, c1 = 1, c2 = 2;   // ring: c0 = current, c2 = stage target
  for (int kt = 0; kt < 16; ++kt) {
    if (kt < 14) {
      STAGE(c2, kt + 2);
      // 8 DMAs (stages kt+1, kt+2) stay in flight; kt's 4 are complete
      asm volatile("s_waitcnt vmcnt(8)\n\ts_barrier" ::: "memory");
    } else if (kt == 14) {
      asm volatile("s_waitcnt vmcnt(4)\n\ts_barrier" ::: "memory");
    } else {
      asm volatile("s_waitcnt vmcnt(0)\n\ts_barrier" ::: "memory");
    }

    short8 af[4], bf[4];
#pragma unroll
    for (int mt = 0; mt < 4; ++mt)
      af[mt] = *(const short8*)&As[c0][(wm * 64 + mt * 16 + fr) * 32 + fq * 8];
#pragma unroll
    for (int nt = 0; nt < 4; ++nt)
      bf[nt] = *(const short8*)&Bs[c0][(wn * 64 + nt * 16 + fr) * 32 + fq * 8];
#pragma unroll
    for (int mt = 0; mt < 4; ++mt)
#pragma unroll
      for (int nt = 0; nt < 4; ++nt)
        acc[mt][nt] = __builtin_amdgcn_mfma_f32_16x16x32_bf16(af[mt], bf[nt], acc[mt][nt], 0, 0, 0);

    // all waves done reading buf c0 before anyone DMAs into it next iter
    asm volatile("s_barrier" ::: "memory");
    const int tmp = c0; c0 = c1; c1 = c2; c2 = tmp;
  }
#undef STAGE

  // epilogue (fp32 out): C/D layout col(n)=lane&15, row(m)=(lane>>4)*4+reg.
#pragma unroll
  for (int nt = 0; nt < 4; ++nt) {
    const int ng = n0 + wn * 64 + nt * 16 + fr;
    const float dv = __expf(-0.03597789208f * (float)(ng >> 1));
    const bool odd = (ng & 1);
#pragma unroll
    for (int mt = 0; mt < 4; ++mt) {
#pragma unroll
      for (int r = 0; r < 4; ++r) {
        const int mg = m0 + wm * 64 + mt * 16 + fq * 4 + r;
        if (mg < NWIN) {
          const int bb = mg / TW_N;
          const int tw = mg - bb * TW_N;
          const float ang = (float)tw * dv;
          const float pev = odd ? __cosf(ang) : __sinf(ang);
          out[((size_t)(bb * 2048 + 1 + tw)) * HID + ng] = acc[mt][nt][r] + pev;
        }
      }
    }
  }
}

extern "C" void kernel_launch(void* const* d_in, const int* in_sizes, int n_in,
                              void* d_out, int out_size, void* d_ws, size_t ws_size,
                              hipStream_t stream)
{
  const float* sig = (const float*)d_in[0];
  const float* chw = (const float*)d_in[1];
  const float* chb = (const float*)d_in[2];
  const float* mxw = (const float*)d_in[3];
  const float* mkr = (const float*)d_in[4];
  float* out = (float*)d_out;

  ushortT* flatB = (ushortT*)d_ws;

  hipLaunchKernelGGL(prep_kernel, dim3(144), dim3(256), 0, stream, mkr, mxw, out);
  hipLaunchKernelGGL(feat_embed_kernel, dim3(4094), dim3(256), 0, stream, sig, chw, chb, flatB);
  hipLaunchKernelGGL(mix_gemm_kernel, dim3(4, 128), dim3(256), 0, stream, flatB, out);
}

// Round 8
// 233.368 us; speedup vs baseline: 1.5259x; 1.0297x over previous
//
#include <hip/hip_runtime.h>
#include <stdint.h>

#define TW_N 2047
#define BATCH 8
#define T_LEN 65536
#define NCH 64
#define HID 512
#define NWIN (BATCH * TW_N) /* 16376 */

typedef unsigned short ushortT;

// ---------- bf16 pack helpers ----------
__device__ __forceinline__ ushortT f2b(float f) {
  union { float f; uint32_t i; } v; v.f = f;
  uint32_t r = v.i + 0x7fffu + ((v.i >> 16) & 1u);
  return (ushortT)(r >> 16);
}
__device__ __forceinline__ uint32_t pk2(float lo, float hi) {
  return (uint32_t)f2b(lo) | ((uint32_t)f2b(hi) << 16);
}

// ---------- async global->LDS, 16B per lane (dest linear in lane order) ----------
__device__ __forceinline__ void gload_lds16(const void* g, void* l) {
  __builtin_amdgcn_global_load_lds(
      (const __attribute__((address_space(1))) uint32_t*)g,
      (__attribute__((address_space(3))) uint32_t*)l, 16, 0, 0);
}

// ---------- compile-time DFT twiddles ----------
constexpr float CQ[17] = {
  1.0f, 0.9951847267f, 0.9807852804f, 0.9569403357f, 0.9238795325f,
  0.8819212643f, 0.8314696123f, 0.7730104534f, 0.7071067812f, 0.6343932842f,
  0.5555702330f, 0.4713967368f, 0.3826834324f, 0.2902846773f, 0.1950903220f,
  0.0980171403f, 0.0f };
constexpr float cos64(int m) {
  m &= 63;
  return (m <= 16) ? CQ[m] : (m < 32) ? -CQ[32 - m] : (m < 48) ? -CQ[m - 32] : CQ[64 - m];
}
constexpr float sin64(int m) { return cos64(m - 16); }
// odd k = 2i+1 (i<12): 32-term DFT over o.  even k = 2j (j=1..12): 16-term DFT
// over (j even ? u : v), twiddle w64^{2jt}.
struct Tw2 { float oc[12][32]; float os[12][32]; float ec[12][16]; float es[12][16]; };
constexpr Tw2 make2() {
  Tw2 t{};
  for (int i = 0; i < 12; ++i)
    for (int tt = 0; tt < 32; ++tt) {
      t.oc[i][tt] = cos64((2 * i + 1) * tt);
      t.os[i][tt] = sin64((2 * i + 1) * tt);
    }
  for (int j = 1; j <= 12; ++j)
    for (int tt = 0; tt < 16; ++tt) {
      t.ec[j - 1][tt] = cos64(2 * j * tt);
      t.es[j - 1][tt] = sin64(2 * j * tt);
    }
  return t;
}
constexpr Tw2 TW = make2();

// bf16-packed mix_w, written once per launch by prep_kernel
__device__ ushortT Bpack[HID * HID];   // 512 KB device-global

// ---------- K0: marker rows + mix_w fp32->bf16 pre-pack ----------
__global__ __launch_bounds__(256) void prep_kernel(
    const float* __restrict__ marker, const float* __restrict__ Bw,
    float* __restrict__ out)
{
  const int gid = blockIdx.x * 256 + threadIdx.x;
  if (blockIdx.x < 16) {
    out[(size_t)(gid >> 9) * (2048 * 512) + (gid & 511)] = marker[gid & 511];
  } else {
    const int i = (gid - 4096) * 8;
    const float4 f0 = *(const float4*)(Bw + i);
    const float4 f1 = *(const float4*)(Bw + i + 4);
    uint4 u;
    u.x = pk2(f0.x, f0.y); u.y = pk2(f0.z, f0.w);
    u.z = pk2(f1.x, f1.y); u.w = pk2(f1.z, f1.w);
    *(uint4*)(Bpack + i) = u;
  }
}

// ---------- K1: LDS-staged, 4 windows/block (1 per wave), lane = channel -----
// 40 KB LDS tile (160 rows x 64 ch), async gload_lds stage, ONE barrier, then
// waves run free. 4 blocks/CU: block i's DMA overlaps block j's compute (no
// CU-wide phase lock -- the round-1 mistake). Compute body identical to r7.
__global__ __launch_bounds__(256) __attribute__((amdgpu_waves_per_eu(4)))
void feat_embed_kernel(
    const float* __restrict__ sig, const float* __restrict__ chw,
    const float* __restrict__ chb, ushortT* __restrict__ flatB)
{
  __shared__ float xs[160 * NCH];   // 40960 B
  const int tid = threadIdx.x;
  const int c = tid & 63;
  const int wv = tid >> 6;
  const int bid = blockIdx.x;       // 0..4095
  const int b = bid >> 9;           // batch
  int tw0 = (bid & 511) * 4;
  if (tw0 > TW_N - 4) tw0 = TW_N - 4;   // block 511: windows 2043..2046
                                        // (2043 dup of block 510 - benign)
  const float* sgb = sig + ((size_t)b * T_LEN + (size_t)tw0 * 32) * NCH;

  // stage 160 rows: 2560 float4 slots, 10 per thread, linear in tid per pass.
  // Last block/batch: rows [65376, 65536) -- exactly in-bounds.
#pragma unroll
  for (int k = 0; k < 10; ++k) {
    const int idx = tid + k * 256;
    gload_lds16(sgb + (size_t)idx * 4, (char*)xs + (size_t)idx * 16);
  }
  __syncthreads();   // compiler emits s_waitcnt vmcnt(0) before s_barrier

  const float* base = xs + (size_t)(wv * 32) * NCH + c;   // 2-way bank alias: free
  const float* wr = chw + c * 56;
  const float* cbp = chb + c * 8;

  float X[32], Y[32];
#pragma unroll
  for (int t = 0; t < 32; ++t) X[t] = base[t * 64];
#pragma unroll
  for (int t = 0; t < 32; ++t) Y[t] = base[(t + 32) * 64];

  // butterfly in place: X <- e = a+d, Y <- o = a-d
  float sum = 0.f, so2 = 0.f, se2 = 0.f;
#pragma unroll
  for (int t = 0; t < 32; ++t) {
    const float e = X[t] + Y[t];
    const float o = X[t] - Y[t];
    X[t] = e; Y[t] = o;
    so2 = fmaf(o, o, so2);
  }
  // second butterfly on e: X[t]=u, X[t+16]=v
#pragma unroll
  for (int t = 0; t < 16; ++t) {
    const float u = X[t] + X[t + 16], v = X[t] - X[t + 16];
    X[t] = u; X[t + 16] = v;
    sum += u;
    se2 = fmaf(u, u, fmaf(v, v, se2));
  }

  // odd k = 2i+1: 32-term DFT over Y = o (t-outer, 24 independent FMA chains)
  float ro[12], io[12];
#pragma unroll
  for (int i = 0; i < 12; ++i) { ro[i] = 0.f; io[i] = 0.f; }
#pragma unroll
  for (int t = 0; t < 32; ++t) {
    const float o = Y[t];
#pragma unroll
    for (int i = 0; i < 12; ++i) {
      ro[i] = fmaf(o, TW.oc[i][t], ro[i]);
      io[i] = fmaf(o, TW.os[i][t], io[i]);
    }
  }
  float b1 = 0.f, b2 = 0.f, b3 = 0.f, b4 = 0.f;
#pragma unroll
  for (int i = 0; i < 12; ++i) {               // odd mags; ro/io + Y die
    const float mag = __builtin_amdgcn_sqrtf(fmaf(ro[i], ro[i], io[i] * io[i]));
    const int k = 2 * i + 1;
    if (k == 1) b1 += mag;
    else if (k < 4) b2 += mag;
    else if (k < 8) b3 += mag;
    else b4 += mag;
  }

  // even k = 2j: 16-term DFT over (j odd ? v : u)
  float re_[12], ie_[12];
#pragma unroll
  for (int j = 0; j < 12; ++j) { re_[j] = 0.f; ie_[j] = 0.f; }
#pragma unroll
  for (int t = 0; t < 16; ++t) {
#pragma unroll
    for (int j = 1; j <= 12; ++j) {
      const float vv = X[(j & 1) * 16 + t];
      re_[j - 1] = fmaf(vv, TW.ec[j - 1][t], re_[j - 1]);
      ie_[j - 1] = fmaf(vv, TW.es[j - 1][t], ie_[j - 1]);
    }
  }
#pragma unroll
  for (int j = 1; j <= 12; ++j) {              // even mags
    const float mag = __builtin_amdgcn_sqrtf(
        fmaf(re_[j - 1], re_[j - 1], ie_[j - 1] * ie_[j - 1]));
    const int k = 2 * j;
    if (k < 4) b2 += mag; else if (k < 8) b3 += mag; else b4 += mag;
  }

  const float mean = sum * (1.f / 64.f);
  const float var =
      (se2 * 0.25f + so2 * 0.5f - sum * sum * (1.f / 64.f)) * (1.f / 63.f);
  const float sd = __builtin_amdgcn_sqrtf(fmaxf(var, 0.f));

  const float f1 = b1, f2 = b2 * 0.5f, f3 = b3 * 0.25f, f4 = b4 * (1.f / 17.f);
  float emb[8];
#pragma unroll
  for (int p = 0; p < 8; ++p) {
    float e = cbp[p];
    e = fmaf(f1, wr[8 + p], e);
    e = fmaf(f2, wr[16 + p], e);
    e = fmaf(f3, wr[24 + p], e);
    e = fmaf(f4, wr[32 + p], e);
    e = fmaf(mean, wr[40 + p], e);
    e = fmaf(sd, wr[48 + p], e);
    emb[p] = e;
  }

  uint32_t pka[4];
#pragma unroll
  for (int q = 0; q < 4; ++q) pka[q] = pk2(emb[2 * q], emb[2 * q + 1]);
  const int w = b * TW_N + tw0 + wv;
  *(uint4*)(flatB + (size_t)w * HID + c * 8) = make_uint4(pka[0], pka[1], pka[2], pka[3]);
}

// ---------- K2: z = flat @ mix_w^T + PE, depth-2 pipelined MFMA GEMM ----------
typedef __attribute__((ext_vector_type(8))) short short8;
typedef __attribute__((ext_vector_type(4))) float f32x4;

__global__ __launch_bounds__(256) void mix_gemm_kernel(
    const ushortT* __restrict__ A,    // flatB [16376][512] bf16 (ws)
    float* __restrict__ out)
{
  __shared__ ushortT As[3][128 * 32];  // 3-buffer ring, 8 KB each side
  __shared__ ushortT Bs[3][128 * 32];

  const int tid = threadIdx.x;
  const int lane = tid & 63;
  const int wv = tid >> 6;
  const int wm = wv >> 1, wn = wv & 1;
  const int fr = lane & 15;
  const int fq = lane >> 4;

  const int n0 = blockIdx.x * 128;   // 4 col-blocks
  const int m0 = blockIdx.y * 128;   // 128 row-blocks

  const int srow = tid >> 2;         // 64 rows per DMA pass
  const int sko = (tid & 3) * 8;     // k-offset in elements

  f32x4 acc[4][4];
#pragma unroll
  for (int i = 0; i < 4; ++i)
#pragma unroll
    for (int j = 0; j < 4; ++j) acc[i][j] = (f32x4){0.f, 0.f, 0.f, 0.f};

  int am0 = m0 + srow;       am0 = am0 < NWIN ? am0 : NWIN - 1;
  int am1 = m0 + 64 + srow;  am1 = am1 < NWIN ? am1 : NWIN - 1;
  const ushortT* ga0 = A + (size_t)am0 * HID + sko;
  const ushortT* ga1 = A + (size_t)am1 * HID + sko;
  const ushortT* gb0 = Bpack + (size_t)(n0 + srow) * HID + sko;
  const ushortT* gb1 = Bpack + (size_t)(n0 + 64 + srow) * HID + sko;

#define STAGE(buf, kt) do {                                                    \
    const int ko_ = (kt) * 32;                                                 \
    gload_lds16(ga0 + ko_, (char*)&As[buf][0] + tid * 16);                     \
    gload_lds16(ga1 + ko_, (char*)&As[buf][0] + 4096 + tid * 16);              \
    gload_lds16(gb0 + ko_, (char*)&Bs[buf][0] + tid * 16);                     \
    gload_lds16(gb1 + ko_, (char*)&Bs[buf][0] + 4096 + tid * 16);              \
  } while (0)

  STAGE(0, 0);
  STAGE(1, 1);

  int c0 = 0, c1 = 1, c2 = 2;   // ring: c0 = current, c2 = stage target
  for (int kt = 0; kt < 16; ++kt) {
    if (kt < 14) {
      STAGE(c2, kt + 2);
      // 8 DMAs (stages kt+1, kt+2) stay in flight; kt's 4 are complete
      asm volatile("s_waitcnt vmcnt(8)\n\ts_barrier" ::: "memory");
    } else if (kt == 14) {
      asm volatile("s_waitcnt vmcnt(4)\n\ts_barrier" ::: "memory");
    } else {
      asm volatile("s_waitcnt vmcnt(0)\n\ts_barrier" ::: "memory");
    }

    short8 af[4], bf[4];
#pragma unroll
    for (int mt = 0; mt < 4; ++mt)
      af[mt] = *(const short8*)&As[c0][(wm * 64 + mt * 16 + fr) * 32 + fq * 8];
#pragma unroll
    for (int nt = 0; nt < 4; ++nt)
      bf[nt] = *(const short8*)&Bs[c0][(wn * 64 + nt * 16 + fr) * 32 + fq * 8];
#pragma unroll
    for (int mt = 0; mt < 4; ++mt)
#pragma unroll
      for (int nt = 0; nt < 4; ++nt)
        acc[mt][nt] = __builtin_amdgcn_mfma_f32_16x16x32_bf16(af[mt], bf[nt], acc[mt][nt], 0, 0, 0);

    // all waves done reading buf c0 before anyone DMAs into it next iter
    asm volatile("s_barrier" ::: "memory");
    const int tmp = c0; c0 = c1; c1 = c2; c2 = tmp;
  }
#undef STAGE

  // epilogue (fp32 out): C/D layout col(n)=lane&15, row(m)=(lane>>4)*4+reg.
#pragma unroll
  for (int nt = 0; nt < 4; ++nt) {
    const int ng = n0 + wn * 64 + nt * 16 + fr;
    const float dv = __expf(-0.03597789208f * (float)(ng >> 1));
    const bool odd = (ng & 1);
#pragma unroll
    for (int mt = 0; mt < 4; ++mt) {
#pragma unroll
      for (int r = 0; r < 4; ++r) {
        const int mg = m0 + wm * 64 + mt * 16 + fq * 4 + r;
        if (mg < NWIN) {
          const int bb = mg / TW_N;
          const int tw = mg - bb * TW_N;
          const float ang = (float)tw * dv;
          const float pev = odd ? __cosf(ang) : __sinf(ang);
          out[((size_t)(bb * 2048 + 1 + tw)) * HID + ng] = acc[mt][nt][r] + pev;
        }
      }
    }
  }
}

extern "C" void kernel_launch(void* const* d_in, const int* in_sizes, int n_in,
                              void* d_out, int out_size, void* d_ws, size_t ws_size,
                              hipStream_t stream)
{
  const float* sig = (const float*)d_in[0];
  const float* chw = (const float*)d_in[1];
  const float* chb = (const float*)d_in[2];
  const float* mxw = (const float*)d_in[3];
  const float* mkr = (const float*)d_in[4];
  float* out = (float*)d_out;

  ushortT* flatB = (ushortT*)d_ws;

  hipLaunchKernelGGL(prep_kernel, dim3(144), dim3(256), 0, stream, mkr, mxw, out);
  hipLaunchKernelGGL(feat_embed_kernel, dim3(4096), dim3(256), 0, stream, sig, chw, chb, flatB);
  hipLaunchKernelGGL(mix_gemm_kernel, dim3(4, 128), dim3(256), 0, stream, flatB, out);
}